// Round 17
// baseline (171.425 us; speedup 1.0000x reference)
//
#include <hip/hip_runtime.h>
#include <hip/hip_bf16.h>
#include <stdint.h>

typedef __hip_bfloat16 bf16_t;
typedef __attribute__((ext_vector_type(8))) __bf16 bf16x8;
typedef __attribute__((ext_vector_type(4))) float f32x4;
typedef __attribute__((ext_vector_type(8))) unsigned short ushort8;
typedef __attribute__((ext_vector_type(2))) unsigned long long u64x2;

#define BM 256
#define BN 256
#define BKT 32
#define THREADS 512
#define OPB 16384      // A region per buffer: 256 rows x 64 B
#define BUFB 32768     // A + B per K-tile buffer
#define LDS_TOTAL 98304  // 3 buffers

// ---------------- fused quantize: q = rint(v*100)/100, cast to bf16 ----------------
// NT loads: x/W read exactly once -> don't evict qA/qB (GEMM re-reads via L2/LLC).
// Agent-scope stores for replay-safe cross-kernel visibility.
__global__ __launch_bounds__(256) void quant2_bf16_kernel(
    const float* __restrict__ x, const float* __restrict__ w,
    bf16_t* __restrict__ q, long axn8, long totn8) {
  long idx = (long)blockIdx.x * blockDim.x + threadIdx.x;
  long stride = (long)gridDim.x * blockDim.x;
  for (long i = idx; i < totn8; i += stride) {
    const float* src = (i < axn8) ? (x + i * 8) : (w + (i - axn8) * 8);
    const f32x4* p = reinterpret_cast<const f32x4*>(src);
    f32x4 v0 = __builtin_nontemporal_load(p);
    f32x4 v1 = __builtin_nontemporal_load(p + 1);
    float vv[8] = {v0[0], v0[1], v0[2], v0[3], v1[0], v1[1], v1[2], v1[3]};
    ushort8 r;
#pragma unroll
    for (int j = 0; j < 8; ++j) {
      float qq = rintf(vv[j] * 100.0f) / 100.0f;  // half-to-even, matches jnp.round
      __hip_bfloat16 h = __float2bfloat16(qq);
      r[j] = __builtin_bit_cast(unsigned short, h);
    }
    u64x2 u = __builtin_bit_cast(u64x2, r);
    unsigned long long* dst = reinterpret_cast<unsigned long long*>(q + i * 8);
    __hip_atomic_store(dst + 0, u[0], __ATOMIC_RELAXED, __HIP_MEMORY_SCOPE_AGENT);
    __hip_atomic_store(dst + 1, u[1], __ATOMIC_RELAXED, __HIP_MEMORY_SCOPE_AGENT);
  }
}

// ---------------- fallback ----------------
__global__ void naive_kernel(const float* __restrict__ x, const float* __restrict__ W,
                             const float* __restrict__ b, float* __restrict__ out,
                             int M, int N, int K) {
  int o = blockIdx.x * blockDim.x + threadIdx.x;
  int m = blockIdx.y;
  if (o >= N || m >= M) return;
  float s = 0.f;
  for (int k = 0; k < K; ++k) {
    float qx = rintf(x[(size_t)m * K + k] * 100.f) / 100.f;
    float qw = rintf(W[(size_t)o * K + k] * 100.f) / 100.f;
    s += qx * qw;
  }
  float v = s + b[o];
  __hip_atomic_store(out + (size_t)m * N + o, v, __ATOMIC_RELAXED,
                     __HIP_MEMORY_SCOPE_AGENT);
}

__device__ __forceinline__ void gload_lds16(const bf16_t* g, const char* l) {
  __builtin_amdgcn_global_load_lds(
      (const __attribute__((address_space(1))) unsigned int*)g,
      (__attribute__((address_space(3))) unsigned int*)l, 16, 0, 0);
}

#define BARRIER()                               \
  do {                                          \
    asm volatile("" ::: "memory");              \
    __builtin_amdgcn_s_barrier();               \
    asm volatile("" ::: "memory");              \
  } while (0)
#define LGKM0() asm volatile("s_waitcnt lgkmcnt(0)" ::: "memory")
#define VM4() asm volatile("s_waitcnt vmcnt(4)" ::: "memory")
#define VM0() asm volatile("s_waitcnt vmcnt(0)" ::: "memory")

// ---------------- bf16 GEMM, B^T input: C[m][n] = sum_k A[m][k]*B[n][k] + bias[n]
// ROUND 17: CARRIED-MFMA windows. Rounds 6-16 (8 variants, 120-131 us, MfmaUtil
// 46-50%) all share one property: the MFMAs consuming a buffer COMPLETE inside
// that buffer's barrier window, so each window's lgkm-wait has no MFMA drain to
// hide under -> LDS pipe (5800 cy/iter) and matrix pipe (4966 cy) run in series.
// m201's core mechanism: reach the barrier right after MFMA ISSUE; the next
// window's ds_read latency overlaps the matrix-pipe drain. That requires the
// consumed buffer to live one window longer -> 3 buffers -> BK=32 (96 KiB LDS).
//
// Window W(t), t=1..nt-1 (one K-tile each; 8 waves, per-wave 128x64 out):
//   if (t+2<nt) { STAGE(t+2 -> buf[(t+2)%3]); VM4; }   // VM4 retires tile t+1
//   else if (t+1<nt) VM0;                              //   (staged 1 window ago)
//   MMA_hi(tile t-1)   // 16 MFMA; operands (aq[4..7],blo,bhi) carried in regs,
//                      //   issue immediately with NO lgkm wait
//   READ b + A-lo (8 b128) -> lgkm-wait overlaps MMA_hi drain
//   MMA_lo(tile t)     // 16 MFMA
//   READ A-hi (4 b128) // consumed next window's MMA_hi
//   LGKM0              // all reads complete before the barrier (else a wave's
//                      //   in-flight ds_read races the next window's stage-DMA)
//   BARRIER
// Epilogue: final MMA_hi(nt-1) after the loop.
//
// Ledger (per-thread loads; STAGE = 4: A 2 + B 2):
//   prologue: STAGE(0,b0) STAGE(1,b1) (+8), VM4 -> retires t0, keeps t1. BAR.
//   W0 (peeled, no MMA_hi): STAGE(2,b2) (+4 -> 8), VM4 -> retires t1 (needed
//     W1), keeps t2; reads t0; MMA_lo(0); reads A-hi(0); LGKM0; BAR.
//   W(t): enter with t+1's 4 in flight; +4 (t+2) -> 8; VM4 retires t+1 (staged
//     W(t-1), ~1 window old > HBM latency). Tail: W(nt-2) has no stage -> VM0
//     drains tile nt-1. RAW: tile t retired at W(t-1)'s VM + barrier. WAR:
//     buf[(t+2)%3] last read in W(t-1); LGKM0-before-barrier guarantees those
//     reads completed before W(t)'s stage-DMA can touch it.
// LDS swizzle (r2-verified geometry, 0 conflicts): 64-B rows, 4 slots of 16 B,
// stored slot = slot ^ ((row>>1)&3); global_load_lds dest linear, inverse
// swizzle on the global SOURCE k-slot (rule #21).
__global__ __launch_bounds__(THREADS, 2) void gemm_bt_bf16(
    const bf16_t* __restrict__ A,   // [M][K]
    const bf16_t* __restrict__ B,   // [N][K]
    const float* __restrict__ bias, // [N]
    float* __restrict__ C,          // [M][N]
    int M, int N, int K) {
  extern __shared__ char lds[];

  const int tid = threadIdx.x;
  const int lane = tid & 63;
  const int wave = tid >> 6;  // 0..7
  const int wm = wave >> 2;   // 0..1 -> output rows wm*128..+128
  const int wn = wave & 3;    // 0..3 -> output cols wn*64..+64
  const int lr = lane & 15;
  const int lg = lane >> 4;

  // XCD-aware bijective swizzle (nwg % 8 == 0 guaranteed by tiled_ok)
  int nbn = N / BN;
  int nwg = gridDim.x;
  int bid = blockIdx.x;
  int swz = bid;
  if ((nwg & 7) == 0) {
    int cpx = nwg >> 3;
    swz = (bid & 7) * cpx + (bid >> 3);
  }
  const int brow = (swz / nbn) * BM;
  const int bcol = (swz % nbn) * BN;

  // ds_read byte offsets (64-B rows; r2-verified swizzle)
  int aoffs[8], boffs[4];
#pragma unroll
  for (int m = 0; m < 8; ++m) {
    int r = wm * 128 + m * 16 + lr;
    aoffs[m] = r * 64 + (((lg) ^ ((r >> 1) & 3)) << 4);
  }
#pragma unroll
  for (int n = 0; n < 4; ++n) {
    int r = wn * 64 + n * 16 + lr;
    boffs[n] = OPB + r * 64 + (((lg) ^ ((r >> 1) & 3)) << 4);
  }

  f32x4 acc[8][4];
#pragma unroll
  for (int m = 0; m < 8; ++m)
#pragma unroll
    for (int n = 0; n < 4; ++n) acc[m][n] = (f32x4){0.f, 0.f, 0.f, 0.f};

  const int nt = K / BKT;

  // Stage one K-tile (A 16 KiB + B 16 KiB = 4 loads/thread). Linear LDS dest;
  // inverse swizzle on the global source k-slot.
  auto STAGE = [&](int kt, int q) {
#pragma unroll
    for (int i = 0; i < 2; ++i) {
      int row = i * 128 + (tid >> 2);
      int L = q * BUFB + row * 64 + ((tid & 3) << 4);
      int slot = (tid & 3) ^ ((row >> 1) & 3);
      gload_lds16(A + (size_t)(brow + row) * K + (size_t)kt * BKT + slot * 8,
                  lds + L);
    }
#pragma unroll
    for (int i = 0; i < 2; ++i) {
      int row = i * 128 + (tid >> 2);
      int L = q * BUFB + OPB + row * 64 + ((tid & 3) << 4);
      int slot = (tid & 3) ^ ((row >> 1) & 3);
      gload_lds16(B + (size_t)(bcol + row) * K + (size_t)kt * BKT + slot * 8,
                  lds + L);
    }
  };

  bf16x8 aq[8], blo[2], bhi[2];  // aq[m]; blo = n0..1, bhi = n2..3 (kk=1 @BK=32)
  auto READ_ALO = [&](int q) {
#pragma unroll
    for (int m = 0; m < 4; ++m)
      aq[m] = *reinterpret_cast<const bf16x8*>(lds + q * BUFB + aoffs[m]);
  };
  auto READ_AHI = [&](int q) {
#pragma unroll
    for (int m = 4; m < 8; ++m)
      aq[m] = *reinterpret_cast<const bf16x8*>(lds + q * BUFB + aoffs[m]);
  };
  auto READ_B2 = [&](int q, int nh, bf16x8* dst) {
#pragma unroll
    for (int nn = 0; nn < 2; ++nn)
      dst[nn] = *reinterpret_cast<const bf16x8*>(lds + q * BUFB + boffs[nh * 2 + nn]);
  };
  // 8 MFMA: one (m-half, n-pair) quadrant of the wave's 128x64 tile.
  auto MMA8 = [&](int mh, int nh, const bf16x8* bb) {
    __builtin_amdgcn_s_setprio(1);
#pragma unroll
    for (int mm = 0; mm < 4; ++mm)
#pragma unroll
      for (int nn = 0; nn < 2; ++nn)
        acc[mh * 4 + mm][nh * 2 + nn] = __builtin_amdgcn_mfma_f32_16x16x32_bf16(
            aq[mh * 4 + mm], bb[nn], acc[mh * 4 + mm][nh * 2 + nn], 0, 0, 0);
    __builtin_amdgcn_s_setprio(0);
  };

  // Prologue: tiles 0,1 staged; VM4 retires tile 0.
  STAGE(0, 0);
  STAGE(1, 1);
  VM4();
  BARRIER();

  // W0 (peeled: no carried MMA_hi).
  {
    if (2 < nt) { STAGE(2, 2); VM4(); }  // retires tile 1 (needed W1)
    else { VM0(); }
    READ_B2(0, 0, blo); READ_B2(0, 1, bhi); READ_ALO(0);
    MMA8(0, 0, blo); MMA8(0, 1, bhi);
    READ_AHI(0);
    LGKM0();
    BARRIER();
  }

  for (int t = 1; t < nt; ++t) {
    const int q = t % 3;
    if (t + 2 < nt) {
      STAGE(t + 2, (t + 2) % 3);
      VM4();          // retires tile t+1 (staged one window ago)
    } else if (t + 1 < nt) {
      VM0();          // drain tile nt-1 before W(nt-1) reads it
    }
    // carried m-hi MFMAs of tile t-1: operands already in regs, issue now;
    // the following reads' lgkm-wait overlaps their drain.
    MMA8(1, 1, bhi); MMA8(1, 0, blo);
    READ_B2(q, 0, blo); READ_B2(q, 1, bhi); READ_ALO(q);
    MMA8(0, 0, blo); MMA8(0, 1, bhi);
    READ_AHI(q);
    LGKM0();   // all reads done before barrier (stage-DMA WAR safety)
    BARRIER();
  }
  // final carried m-hi of tile nt-1
  MMA8(1, 1, bhi); MMA8(1, 0, blo);

  // Epilogue: C/D layout col=lane&15, row=(lane>>4)*4+reg  [m89/m91]
  // Agent-scope stores (replay-safe visibility past per-XCD L2).
  const int cn = lane & 15;
  const int r4 = (lane >> 4) << 2;
#pragma unroll
  for (int n = 0; n < 4; ++n) {
    const int gcol = bcol + wn * 64 + n * 16 + cn;
    const float bv = bias[gcol];
#pragma unroll
    for (int m = 0; m < 8; ++m) {
      const int grow = brow + wm * 128 + m * 16 + r4;
      float* outp = C + (size_t)grow * N + gcol;
#pragma unroll
      for (int j = 0; j < 4; ++j) {
        float v = acc[m][n][j] + bv;
        __hip_atomic_store(outp + (size_t)j * N, v, __ATOMIC_RELAXED,
                           __HIP_MEMORY_SCOPE_AGENT);
      }
    }
  }
}

extern "C" void kernel_launch(void* const* d_in, const int* in_sizes, int n_in,
                              void* d_out, int out_size, void* d_ws, size_t ws_size,
                              hipStream_t stream) {
  const float* x = (const float*)d_in[0];
  const float* W = (const float*)d_in[1];
  const float* b = (const float*)d_in[2];
  float* out = (float*)d_out;

  const int N = in_sizes[2];       // D_OUT
  const int K = in_sizes[1] / N;   // D_IN
  const int M = in_sizes[0] / K;   // B rows

  const size_t needA = (size_t)M * K * sizeof(bf16_t);
  const size_t needB = (size_t)N * K * sizeof(bf16_t);
  const bool tiled_ok = (M % BM == 0) && (N % BN == 0) && (K % BKT == 0) &&
                        (K / BKT >= 2) && (ws_size >= needA + needB);
  if (!tiled_ok) {
    dim3 g((unsigned)((N + 255) / 256), (unsigned)M);
    naive_kernel<<<g, 256, 0, stream>>>(x, W, b, out, M, N, K);
    return;
  }

  bf16_t* qA = (bf16_t*)d_ws;
  bf16_t* qB = qA + (size_t)M * K;
  const long axn8 = (long)M * K / 8;
  const long totn8 = axn8 + (long)N * K / 8;
  quant2_bf16_kernel<<<2048, 256, 0, stream>>>(x, W, qA, axn8, totn8);

  (void)hipFuncSetAttribute((const void*)gemm_bt_bf16,
                            hipFuncAttributeMaxDynamicSharedMemorySize, LDS_TOTAL);

  const int nwg = (M / BM) * (N / BN);
  gemm_bt_bf16<<<nwg, THREADS, LDS_TOTAL, stream>>>(qA, qB, b, out, M, N, K);
}

// Round 18
// 152.884 us; speedup vs baseline: 1.1213x; 1.1213x over previous
//
#include <hip/hip_runtime.h>
#include <hip/hip_bf16.h>
#include <stdint.h>

typedef __hip_bfloat16 bf16_t;
typedef __attribute__((ext_vector_type(8))) __bf16 bf16x8;
typedef __attribute__((ext_vector_type(4))) float f32x4;
typedef __attribute__((ext_vector_type(8))) unsigned short ushort8;
typedef __attribute__((ext_vector_type(2))) unsigned long long u64x2;

#define BM 256
#define BN 256
#define BK 64
#define THREADS 512
#define OPBYTES 32768   // one operand per buf: 256 rows x 128 B
#define BUFBYTES 65536  // A + B
#define LDS_TOTAL 131072

// ---------------- fused quantize: q = rint(v*100)/100, cast to bf16 ----------------
// NT loads: x/W are read exactly once. NT STORES for qA/qB: single 16-B
// write-combined store, no dirty per-XCD L2 lines (write-through to L3/HBM),
// so the GEMM kernel on any XCD reads fresh data under graph replay — strictly
// safer than plain cached stores (r1's failure mode was dirty-L2 visibility),
// and cheaper than the 2x 8-B agent-scope atomics used r2-r17.
__global__ __launch_bounds__(256) void quant2_bf16_kernel(
    const float* __restrict__ x, const float* __restrict__ w,
    bf16_t* __restrict__ q, long axn8, long totn8) {
  long idx = (long)blockIdx.x * blockDim.x + threadIdx.x;
  long stride = (long)gridDim.x * blockDim.x;
  for (long i = idx; i < totn8; i += stride) {
    const float* src = (i < axn8) ? (x + i * 8) : (w + (i - axn8) * 8);
    const f32x4* p = reinterpret_cast<const f32x4*>(src);
    f32x4 v0 = __builtin_nontemporal_load(p);
    f32x4 v1 = __builtin_nontemporal_load(p + 1);
    float vv[8] = {v0[0], v0[1], v0[2], v0[3], v1[0], v1[1], v1[2], v1[3]};
    ushort8 r;
#pragma unroll
    for (int j = 0; j < 8; ++j) {
      float qq = rintf(vv[j] * 100.0f) / 100.0f;  // half-to-even, matches jnp.round
      __hip_bfloat16 h = __float2bfloat16(qq);
      r[j] = __builtin_bit_cast(unsigned short, h);
    }
    u64x2 u = __builtin_bit_cast(u64x2, r);
    u64x2* dst = reinterpret_cast<u64x2*>(q + i * 8);
    __builtin_nontemporal_store(u, dst);
  }
}

// ---------------- fallback ----------------
__global__ void naive_kernel(const float* __restrict__ x, const float* __restrict__ W,
                             const float* __restrict__ b, float* __restrict__ out,
                             int M, int N, int K) {
  int o = blockIdx.x * blockDim.x + threadIdx.x;
  int m = blockIdx.y;
  if (o >= N || m >= M) return;
  float s = 0.f;
  for (int k = 0; k < K; ++k) {
    float qx = rintf(x[(size_t)m * K + k] * 100.f) / 100.f;
    float qw = rintf(W[(size_t)o * K + k] * 100.f) / 100.f;
    s += qx * qw;
  }
  float v = s + b[o];
  __hip_atomic_store(out + (size_t)m * N + o, v, __ATOMIC_RELAXED,
                     __HIP_MEMORY_SCOPE_AGENT);
}

__device__ __forceinline__ void gload_lds16(const bf16_t* g, const char* l) {
  __builtin_amdgcn_global_load_lds(
      (const __attribute__((address_space(1))) unsigned int*)g,
      (__attribute__((address_space(3))) unsigned int*)l, 16, 0, 0);
}

#define BARRIER()                               \
  do {                                          \
    asm volatile("" ::: "memory");              \
    __builtin_amdgcn_s_barrier();               \
    asm volatile("" ::: "memory");              \
  } while (0)
#define VM8() asm volatile("s_waitcnt vmcnt(8)" ::: "memory")
#define VM0() asm volatile("s_waitcnt vmcnt(0)" ::: "memory")

// ---------------- bf16 GEMM, B^T input: C[m][n] = sum_k A[m][k]*B[n][k] + bias[n]
// FINAL CONFIG (= round 16, equal-best measured: 120.0-120.5 us GEMM,
// MfmaUtil 48.8-49.8, 0 bank conflicts). 4 superphases/iter, deep VM8
// prefetch, tail/interleaved reads, compiler-managed lgkmcnt.
// Campaign record at this geometry (256^2 tile, 8 waves, BK=64, 2 LDS bufs):
//   r9 wide 4-phase -41%; r10 2-blocks/CU -15%; r13 32x32 MFMA -18% (inherent
//   4-way LDS conflicts at 128B rows); r14 two-barrier m201 port -7%;
//   r17 carried-MFMA/BK=32 -6%; r8/r11/r12/r16 variants within noise.
// Cycle model: matrix pipe 4966 cy/iter (256 MFMA/SIMD x 19.4cy), LDS pipe
// ~5600 cy/iter (CU-shared); measured 9100 = serial sum. Barrier-synced
// schedules keep all 8 waves' read-bursts phase-aligned, so the pipes
// alternate; every HIP-source attempt to break the lockstep was null or
// negative. This is the structure-class ceiling at plain-HIP level.
//
// Superphases (buf0; buf1 mirrors):
//   A = { 12 reads; MMA(0,0); 4 reads; MMA(0,1); 8 reads }  BARRIER
//   B = { stage B(t2); MMA(1,1); stage A(t2); MMA(1,0); VM8 }  BARRIER
// Hazards: (1) A-end barrier: all buf0 reads < buf0 stages (WAR).
// (2) B-end barrier after VM8: b1(t1) landed < buf1 reads (RAW; those loads
// are 4-6 phases old => no stall). Prologue: both tiles staged (16 loads),
// VM8 retires b0. PEELED last iter: no stages; VM0 in B0.
// LDS swizzle: 128B rows, stored slot = slot ^ (row&7) (0 conflicts measured
// r2-r16). global_load_lds dest linear (base+lane*16); swizzle applied on the
// global SOURCE address (rule #21).
__global__ __launch_bounds__(THREADS, 2) void gemm_bt_bf16(
    const bf16_t* __restrict__ A,   // [M][K]
    const bf16_t* __restrict__ B,   // [N][K]
    const float* __restrict__ bias, // [N]
    float* __restrict__ C,          // [M][N]
    int M, int N, int K) {
  extern __shared__ char lds[];

  const int tid = threadIdx.x;
  const int lane = tid & 63;
  const int wave = tid >> 6;  // 0..7
  const int wm = wave >> 2;   // 0..1 -> output rows wm*128..+128
  const int wn = wave & 3;    // 0..3 -> output cols wn*64..+64
  const int lr = lane & 15;
  const int lg = lane >> 4;

  // XCD-aware bijective swizzle (nwg % 8 == 0 guaranteed by tiled_ok)
  int nbn = N / BN;
  int nwg = gridDim.x;
  int bid = blockIdx.x;
  int swz = bid;
  if ((nwg & 7) == 0) {
    int cpx = nwg >> 3;
    swz = (bid & 7) * cpx + (bid >> 3);
  }
  const int brow = (swz / nbn) * BM;
  const int bcol = (swz % nbn) * BN;

  // ds_read byte offsets within an operand region (kk=0; kk=1 is ^64)
  int aoffs[8], boffs[4];
#pragma unroll
  for (int m = 0; m < 8; ++m) {
    int r = wm * 128 + m * 16 + lr;
    aoffs[m] = r * 128 + (((lg) ^ (r & 7)) << 4);
  }
#pragma unroll
  for (int n = 0; n < 4; ++n) {
    int r = wn * 64 + n * 16 + lr;
    boffs[n] = r * 128 + (((lg) ^ (r & 7)) << 4);
  }

  f32x4 acc[8][4];
#pragma unroll
  for (int m = 0; m < 8; ++m)
#pragma unroll
    for (int n = 0; n < 4; ++n) acc[m][n] = (f32x4){0.f, 0.f, 0.f, 0.f};

  const int nt = K / BK;

  auto STAGE_A = [&](int h, int kt, int q) {
#pragma unroll
    for (int i = 0; i < 2; ++i) {
      int row = h * 128 + i * 64 + (tid >> 3);
      int L = q * BUFBYTES + row * 128 + ((tid & 7) << 4);
      int slot = (tid & 7) ^ (row & 7);
      gload_lds16(A + (size_t)(brow + row) * K + (size_t)kt * 64 + slot * 8,
                  lds + L);
    }
  };
  auto STAGE_B = [&](int h, int kt, int q) {
#pragma unroll
    for (int i = 0; i < 2; ++i) {
      int row = h * 128 + i * 64 + (tid >> 3);
      int L = q * BUFBYTES + OPBYTES + row * 128 + ((tid & 7) << 4);
      int slot = (tid & 7) ^ (row & 7);
      gload_lds16(B + (size_t)(bcol + row) * K + (size_t)kt * 64 + slot * 8,
                  lds + L);
    }
  };

  bf16x8 aq[8], blo[4], bhi[4];  // A quadrant [mm][kk]; B quadrants [nn][kk]
  auto READ_A = [&](int q, int mh) {
#pragma unroll
    for (int mm = 0; mm < 4; ++mm) {
      int off = q * BUFBYTES + aoffs[mh * 4 + mm];
      aq[mm * 2 + 0] = *reinterpret_cast<const bf16x8*>(lds + off);
      aq[mm * 2 + 1] = *reinterpret_cast<const bf16x8*>(lds + (off ^ 64));
    }
  };
  auto READ_B = [&](int q, int nh, bf16x8* dst) {
#pragma unroll
    for (int nn = 0; nn < 2; ++nn) {
      int off = q * BUFBYTES + OPBYTES + boffs[nh * 2 + nn];
      dst[nn * 2 + 0] = *reinterpret_cast<const bf16x8*>(lds + off);
      dst[nn * 2 + 1] = *reinterpret_cast<const bf16x8*>(lds + (off ^ 64));
    }
  };
  auto MMA = [&](int mh, int nh, const bf16x8* bb) {
    __builtin_amdgcn_s_setprio(1);
#pragma unroll
    for (int mm = 0; mm < 4; ++mm)
#pragma unroll
      for (int nn = 0; nn < 2; ++nn)
#pragma unroll
        for (int kk = 0; kk < 2; ++kk)
          acc[mh * 4 + mm][nh * 2 + nn] = __builtin_amdgcn_mfma_f32_16x16x32_bf16(
              aq[mm * 2 + kk], bb[nn * 2 + kk], acc[mh * 4 + mm][nh * 2 + nn],
              0, 0, 0);
    __builtin_amdgcn_s_setprio(0);
  };

  // Prologue: both tiles fully staged; b0's 8 retired, b1's 8 carried in flight.
  STAGE_B(0, 0, 0); STAGE_B(1, 0, 0); STAGE_A(0, 0, 0); STAGE_A(1, 0, 0);
  STAGE_B(0, 1, 1); STAGE_B(1, 1, 1); STAGE_A(0, 1, 1); STAGE_A(1, 1, 1);
  VM8();
  BARRIER();

  const int np = nt >> 1;
  for (int p = 0; p < np - 1; ++p) {
    const int t2 = 2 * p + 2, t3 = 2 * p + 3;
    // superphase A0: ALL buf0 reads interleaved with the m-lo MFMAs.
    READ_B(0, 0, blo); READ_A(0, 0);
    MMA(0, 0, blo);
    READ_B(0, 1, bhi);
    MMA(0, 1, bhi);
    READ_A(0, 1);
    BARRIER();  // (1) all buf0 reads < buf0 stages
    // superphase B0: stages b0<-t2 + m-hi MFMAs; VM8 retires b1(t1).
    STAGE_B(0, t2, 0); STAGE_B(1, t2, 0);
    MMA(1, 1, bhi);
    STAGE_A(0, t2, 0); STAGE_A(1, t2, 0);
    MMA(1, 0, blo);
    VM8();
    BARRIER();  // (2) b1(t1) landed < buf1 reads
    // superphase A1: mirror on buf1.
    READ_B(1, 0, blo); READ_A(1, 0);
    MMA(0, 0, blo);
    READ_B(1, 1, bhi);
    MMA(0, 1, bhi);
    READ_A(1, 1);
    BARRIER();  // (3)
    // superphase B1: stages b1<-t3; VM8 retires b0(t2).
    STAGE_B(0, t3, 1); STAGE_B(1, t3, 1);
    MMA(1, 1, bhi);
    STAGE_A(0, t3, 1); STAGE_A(1, t3, 1);
    MMA(1, 0, blo);
    VM8();
    BARRIER();  // (4)
  }

  // Peeled final iteration: no stages; VM0 in B0 (drains carried b1 loads).
  {
    READ_B(0, 0, blo); READ_A(0, 0);
    MMA(0, 0, blo);
    READ_B(0, 1, bhi);
    MMA(0, 1, bhi);
    READ_A(0, 1);
    BARRIER();
    MMA(1, 1, bhi);
    MMA(1, 0, blo);
    VM0();
    BARRIER();
    READ_B(1, 0, blo); READ_A(1, 0);
    MMA(0, 0, blo);
    READ_B(1, 1, bhi);
    MMA(0, 1, bhi);
    READ_A(1, 1);
    BARRIER();
    MMA(1, 1, bhi);
    MMA(1, 0, blo);
  }

  // Epilogue: C/D layout col=lane&15, row=(lane>>4)*4+reg  [m89/m91]
  // Agent-scope stores (replay-safe visibility past per-XCD L2).
  const int cn = lane & 15;
  const int r4 = (lane >> 4) << 2;
#pragma unroll
  for (int n = 0; n < 4; ++n) {
    const int gcol = bcol + wn * 64 + n * 16 + cn;
    const float bv = bias[gcol];
#pragma unroll
    for (int m = 0; m < 8; ++m) {
      const int grow = brow + wm * 128 + m * 16 + r4;
      float* outp = C + (size_t)grow * N + gcol;
#pragma unroll
      for (int j = 0; j < 4; ++j) {
        float v = acc[m][n][j] + bv;
        __hip_atomic_store(outp + (size_t)j * N, v, __ATOMIC_RELAXED,
                           __HIP_MEMORY_SCOPE_AGENT);
      }
    }
  }
}

extern "C" void kernel_launch(void* const* d_in, const int* in_sizes, int n_in,
                              void* d_out, int out_size, void* d_ws, size_t ws_size,
                              hipStream_t stream) {
  const float* x = (const float*)d_in[0];
  const float* W = (const float*)d_in[1];
  const float* b = (const float*)d_in[2];
  float* out = (float*)d_out;

  const int N = in_sizes[2];       // D_OUT
  const int K = in_sizes[1] / N;   // D_IN
  const int M = in_sizes[0] / K;   // B rows

  const size_t needA = (size_t)M * K * sizeof(bf16_t);
  const size_t needB = (size_t)N * K * sizeof(bf16_t);
  const bool tiled_ok = (M % BM == 0) && (N % BN == 0) && (K % (2 * BK) == 0) &&
                        (K / BK >= 2) && (ws_size >= needA + needB);
  if (!tiled_ok) {
    dim3 g((unsigned)((N + 255) / 256), (unsigned)M);
    naive_kernel<<<g, 256, 0, stream>>>(x, W, b, out, M, N, K);
    return;
  }

  bf16_t* qA = (bf16_t*)d_ws;
  bf16_t* qB = qA + (size_t)M * K;
  const long axn8 = (long)M * K / 8;
  const long totn8 = axn8 + (long)N * K / 8;
  quant2_bf16_kernel<<<2048, 256, 0, stream>>>(x, W, qA, axn8, totn8);

  (void)hipFuncSetAttribute((const void*)gemm_bt_bf16,
                            hipFuncAttributeMaxDynamicSharedMemorySize, LDS_TOTAL);

  const int nwg = (M / BM) * (N / BN);
  gemm_bt_bf16<<<nwg, THREADS, LDS_TOTAL, stream>>>(qA, qB, b, out, M, N, K);
}